// Round 1
// baseline (232.862 us; speedup 1.0000x reference)
//
#include <hip/hip_runtime.h>

// PointPillarScatter: out[b][c][y][x] = feat[p][c] where coords[p]=(x,y,b), else 0.
// Strategy: build flat->pillar map in ws, then a single gather pass writes the
// whole output exactly once with full-wave coalesced stores (fused zero-fill).

#define C_CH 64

__global__ void build_map_kernel(const int* __restrict__ coords, int n_pillars,
                                 const int* __restrict__ nx_p,
                                 const int* __restrict__ ny_p,
                                 int* __restrict__ map) {
    int p = blockIdx.x * blockDim.x + threadIdx.x;
    if (p >= n_pillars) return;
    const int nx = nx_p[0];
    const int ny = ny_p[0];
    const int x = coords[3 * p + 0];
    const int y = coords[3 * p + 1];
    const int b = coords[3 * p + 2];
    const long long m = (long long)b * (long long)(nx * ny) + (long long)y * nx + x;
    map[m] = p;
}

// One thread per (b, y, x) grid cell. Reads map once, stages all 64 channel
// values in registers, then stores 64 wave-coalesced floats (stride = plane).
__global__ void gather64_kernel(const float* __restrict__ feat,
                                const int* __restrict__ map,
                                const int* __restrict__ nx_p,
                                const int* __restrict__ ny_p,
                                float* __restrict__ out, int n_map) {
    const int tid = blockIdx.x * blockDim.x + threadIdx.x;
    if (tid >= n_map) return;
    const int plane = nx_p[0] * ny_p[0];   // uniform
    const int b = tid / plane;
    const int rem = tid - b * plane;
    const size_t base = (size_t)b * C_CH * (size_t)plane + (size_t)rem;

    const int p = map[tid];

    float vals[C_CH];
#pragma unroll
    for (int c = 0; c < C_CH; ++c) vals[c] = 0.0f;

    if (p >= 0) {
        const float4* __restrict__ src =
            (const float4*)(feat + (size_t)p * C_CH);
#pragma unroll
        for (int i = 0; i < C_CH / 4; ++i) {
            float4 v = src[i];
            vals[4 * i + 0] = v.x;
            vals[4 * i + 1] = v.y;
            vals[4 * i + 2] = v.z;
            vals[4 * i + 3] = v.w;
        }
    }

#pragma unroll
    for (int c = 0; c < C_CH; ++c) {
        out[base + (size_t)c * (size_t)plane] = vals[c];
    }
}

// Fallback: direct scatter after zeroing the output (used only if ws is too
// small for the map or C != 64).
__global__ void direct_scatter_kernel(const float* __restrict__ feat,
                                      const int* __restrict__ coords,
                                      int n_pillars, int C,
                                      const int* __restrict__ nx_p,
                                      const int* __restrict__ ny_p,
                                      float* __restrict__ out) {
    const long long t = (long long)blockIdx.x * blockDim.x + threadIdx.x;
    if (t >= (long long)n_pillars * C) return;
    const int p = (int)(t / C);
    const int c = (int)(t - (long long)p * C);
    const int nx = nx_p[0];
    const int ny = ny_p[0];
    const int x = coords[3 * p + 0];
    const int y = coords[3 * p + 1];
    const int b = coords[3 * p + 2];
    const int plane = nx * ny;
    const size_t o = ((size_t)b * C + c) * (size_t)plane + (size_t)y * nx + x;
    out[o] = feat[(size_t)p * C + c];
}

extern "C" void kernel_launch(void* const* d_in, const int* in_sizes, int n_in,
                              void* d_out, int out_size, void* d_ws, size_t ws_size,
                              hipStream_t stream) {
    const float* feat   = (const float*)d_in[0];
    const int*   coords = (const int*)d_in[1];
    // d_in[2] = batch_size (unused on host; implied by out_size), d_in[3] = nx,
    // d_in[4] = ny — device-resident scalars, read inside the kernels.
    const int* nx_p = (const int*)d_in[3];
    const int* ny_p = (const int*)d_in[4];
    float* out = (float*)d_out;

    const int n_pillars = in_sizes[1] / 3;
    const int C = in_sizes[0] / n_pillars;
    const int n_map = out_size / C;                 // B * NY * NX
    const size_t map_bytes = (size_t)n_map * sizeof(int);

    if (C == C_CH && ws_size >= map_bytes) {
        int* map = (int*)d_ws;
        // 0xFF bytes -> every map entry == -1
        hipMemsetAsync(map, 0xFF, map_bytes, stream);
        build_map_kernel<<<(n_pillars + 255) / 256, 256, 0, stream>>>(
            coords, n_pillars, nx_p, ny_p, map);
        gather64_kernel<<<(n_map + 255) / 256, 256, 0, stream>>>(
            feat, map, nx_p, ny_p, out, n_map);
    } else {
        hipMemsetAsync(out, 0, (size_t)out_size * sizeof(float), stream);
        const long long total = (long long)n_pillars * C;
        direct_scatter_kernel<<<(unsigned)((total + 255) / 256), 256, 0, stream>>>(
            feat, coords, n_pillars, C, nx_p, ny_p, out);
    }
}